// Round 5
// baseline (442.585 us; speedup 1.0000x reference)
//
#include <hip/hip_runtime.h>
#include <math.h>

// ---------------------------------------------------------------------------
// 3-layer GCN forward.
//   1. deg count (int atomics over edge dst)
//   2. two-level exclusive scan -> rowptr + cursor (+ fused dinv)
//      (scan temporaries alias buf1, which is dead until the first GEMM)
//   3. CSR fill (scatter src ids by dst)
//   4. per layer: GEMM (h = X@W scaled by dinv[row], stored CHUNK-MAJOR
//      [chunk][node][16]) then XCD-local chunked gather-aggregate:
//      block b handles feature-chunk b%8 -> lands on XCD b%8 (round-robin
//      dispatch), whose 3.2 MB slice stays L2-resident. agg writes row-major.
// ---------------------------------------------------------------------------

__global__ void count_kernel(const int* __restrict__ col, int* __restrict__ deg, int E, int n) {
    int e = blockIdx.x * blockDim.x + threadIdx.x;
    if (e < E) {
        int c = col[e];
        if ((unsigned)c < (unsigned)n) atomicAdd(&deg[c], 1);
    }
}

__global__ __launch_bounds__(256) void scan1_kernel(const int* __restrict__ deg,
                                                    int* __restrict__ local,
                                                    int* __restrict__ blocksums, int n) {
    __shared__ int wsum[4];
    const int t = threadIdx.x;
    const int lane = t & 63;
    const int wv = t >> 6;
    const int base = blockIdx.x * 1024 + t * 4;
    int a0 = (base + 0 < n) ? deg[base + 0] : 0;
    int a1 = (base + 1 < n) ? deg[base + 1] : 0;
    int a2 = (base + 2 < n) ? deg[base + 2] : 0;
    int a3 = (base + 3 < n) ? deg[base + 3] : 0;
    const int tot = a0 + a1 + a2 + a3;
    int incl = tot;
#pragma unroll
    for (int off = 1; off < 64; off <<= 1) {
        int u = __shfl_up(incl, off);
        if (lane >= off) incl += u;
    }
    if (lane == 63) wsum[wv] = incl;
    __syncthreads();
    int woff = 0;
#pragma unroll
    for (int w = 0; w < 4; ++w) woff += (w < wv) ? wsum[w] : 0;
    const int excl = woff + incl - tot;
    if (base + 0 < n) local[base + 0] = excl;
    if (base + 1 < n) local[base + 1] = excl + a0;
    if (base + 2 < n) local[base + 2] = excl + a0 + a1;
    if (base + 3 < n) local[base + 3] = excl + a0 + a1 + a2;
    if (t == 255) blocksums[blockIdx.x] = woff + incl;
}

__global__ void scan2_kernel(const int* __restrict__ blocksums, int* __restrict__ blockoff,
                             int* __restrict__ rowptr, int nb, int n) {
    const int lane = threadIdx.x;  // 64 threads
    int v = (lane < nb) ? blocksums[lane] : 0;
    int incl = v;
#pragma unroll
    for (int off = 1; off < 64; off <<= 1) {
        int u = __shfl_up(incl, off);
        if (lane >= off) incl += u;
    }
    if (lane < nb) blockoff[lane] = incl - v;
    if (lane == 63) rowptr[n] = incl;
}

__global__ void scan3_kernel(const int* __restrict__ local, const int* __restrict__ blockoff,
                             const int* __restrict__ deg, int* __restrict__ rowptr,
                             int* __restrict__ cursor, float* __restrict__ dinv, int n) {
    int i = blockIdx.x * blockDim.x + threadIdx.x;
    if (i < n) {
        const int v = local[i] + blockoff[i >> 10];
        rowptr[i] = v;
        cursor[i] = v;
        dinv[i] = rsqrtf((float)deg[i] + 1.0f);
    }
}

__global__ void fill_kernel(const int* __restrict__ row, const int* __restrict__ col,
                            int* __restrict__ cursor, int* __restrict__ csr, int E, int n) {
    int e = blockIdx.x * blockDim.x + threadIdx.x;
    if (e < E) {
        int c = col[e];
        int r = row[e];
        if ((unsigned)c < (unsigned)n && (unsigned)r < (unsigned)n) {
            int pos = atomicAdd(&cursor[c], 1);
            csr[pos] = r;
        }
    }
}

// h = X @ W (row r scaled by dinv[r]), output stored CHUNK-MAJOR:
// out[(cq/4)*n*16 + row*16 + (cq%4)*4 .. +3]   (chunk = 16 floats)
template <int OUT>
__global__ __launch_bounds__(256) void gemm_kernel(const float* __restrict__ X,
                                                   const float* __restrict__ W,
                                                   const float* __restrict__ dinv,
                                                   float* __restrict__ out, int n) {
    __shared__ float Wl[128 * OUT];
    const int t = threadIdx.x;
    for (int i = t; i < 128 * OUT; i += 256) Wl[i] = W[i];
    __syncthreads();

    constexpr int CQ  = OUT / 4;
    constexpr int RG  = 256 / CQ;
    constexpr int R   = 4;
    constexpr int RPI = RG * R;
    const int cq = t % CQ;
    const int rg = t / CQ;
    const float4* X4 = (const float4*)X;
    const size_t chunk_off = (size_t)(cq >> 2) * n * 16 + (cq & 3) * 4;

    for (int base = blockIdx.x * RPI; base < n; base += gridDim.x * RPI) {
        const int r0 = base + rg * R;
        float4 acc[R];
#pragma unroll
        for (int r = 0; r < R; ++r) acc[r] = make_float4(0.f, 0.f, 0.f, 0.f);

        if (r0 + R <= n) {
#pragma unroll 4
            for (int k4 = 0; k4 < 32; ++k4) {
                const float* wp = &Wl[k4 * 4 * OUT + cq * 4];
                float4 w0 = *(const float4*)(wp);
                float4 w1 = *(const float4*)(wp + OUT);
                float4 w2 = *(const float4*)(wp + 2 * OUT);
                float4 w3 = *(const float4*)(wp + 3 * OUT);
#pragma unroll
                for (int r = 0; r < R; ++r) {
                    float4 xv = X4[(size_t)(r0 + r) * 32 + k4];
                    acc[r].x = fmaf(xv.x, w0.x, acc[r].x);
                    acc[r].x = fmaf(xv.y, w1.x, acc[r].x);
                    acc[r].x = fmaf(xv.z, w2.x, acc[r].x);
                    acc[r].x = fmaf(xv.w, w3.x, acc[r].x);
                    acc[r].y = fmaf(xv.x, w0.y, acc[r].y);
                    acc[r].y = fmaf(xv.y, w1.y, acc[r].y);
                    acc[r].y = fmaf(xv.z, w2.y, acc[r].y);
                    acc[r].y = fmaf(xv.w, w3.y, acc[r].y);
                    acc[r].z = fmaf(xv.x, w0.z, acc[r].z);
                    acc[r].z = fmaf(xv.y, w1.z, acc[r].z);
                    acc[r].z = fmaf(xv.z, w2.z, acc[r].z);
                    acc[r].z = fmaf(xv.w, w3.z, acc[r].z);
                    acc[r].w = fmaf(xv.x, w0.w, acc[r].w);
                    acc[r].w = fmaf(xv.y, w1.w, acc[r].w);
                    acc[r].w = fmaf(xv.z, w2.w, acc[r].w);
                    acc[r].w = fmaf(xv.w, w3.w, acc[r].w);
                }
            }
#pragma unroll
            for (int r = 0; r < R; ++r) {
                const float s = dinv[r0 + r];
                acc[r].x *= s; acc[r].y *= s; acc[r].z *= s; acc[r].w *= s;
                *(float4*)&out[chunk_off + (size_t)(r0 + r) * 16] = acc[r];
            }
        } else if (r0 < n) {
            for (int r = 0; r < R; ++r) {
                const int row = r0 + r;
                if (row >= n) break;
                float4 a = make_float4(0.f, 0.f, 0.f, 0.f);
                for (int k4 = 0; k4 < 32; ++k4) {
                    float4 xv = X4[(size_t)row * 32 + k4];
                    const float* wp = &Wl[k4 * 4 * OUT + cq * 4];
                    float4 w0 = *(const float4*)(wp);
                    float4 w1 = *(const float4*)(wp + OUT);
                    float4 w2 = *(const float4*)(wp + 2 * OUT);
                    float4 w3 = *(const float4*)(wp + 3 * OUT);
                    a.x = fmaf(xv.x, w0.x, a.x); a.x = fmaf(xv.y, w1.x, a.x);
                    a.x = fmaf(xv.z, w2.x, a.x); a.x = fmaf(xv.w, w3.x, a.x);
                    a.y = fmaf(xv.x, w0.y, a.y); a.y = fmaf(xv.y, w1.y, a.y);
                    a.y = fmaf(xv.z, w2.y, a.y); a.y = fmaf(xv.w, w3.y, a.y);
                    a.z = fmaf(xv.x, w0.z, a.z); a.z = fmaf(xv.y, w1.z, a.z);
                    a.z = fmaf(xv.z, w2.z, a.z); a.z = fmaf(xv.w, w3.z, a.z);
                    a.w = fmaf(xv.x, w0.w, a.w); a.w = fmaf(xv.y, w1.w, a.w);
                    a.w = fmaf(xv.z, w2.w, a.w); a.w = fmaf(xv.w, w3.w, a.w);
                }
                const float s = dinv[row];
                a.x *= s; a.y *= s; a.z *= s; a.w *= s;
                *(float4*)&out[chunk_off + (size_t)row * 16] = a;
            }
        }
    }
}

// Chunked XCD-local aggregate. Input hc is chunk-major [NC][n][16].
// Block b: xcd-slot = b%8 -> chunk cc = slot%NC, node-split = slot/NC.
// Each 16-lane group handles one node for one 16-float chunk.
// out is ROW-MAJOR [n][NC*16].
template <int NC, bool RELU>
__global__ __launch_bounds__(256) void agg_chunk_kernel(const float* __restrict__ hc,
                                                        const int* __restrict__ rowptr,
                                                        const int* __restrict__ csr,
                                                        const float* __restrict__ dinv,
                                                        const float* __restrict__ bias,
                                                        float* __restrict__ out, int n) {
    constexpr int F = NC * 16;
    constexpr int NSPLIT = 8 / NC;
    const int t = threadIdx.x;
    const int slot = blockIdx.x & 7;
    const int cc = slot % NC;
    const int split = slot / NC;
    const int g = (blockIdx.x >> 3) * NSPLIT + split;   // node-group id
    const int node = g * 16 + (t >> 4);
    const int ln = t & 15;
    if (node >= n) return;

    const float* __restrict__ slice = hc + (size_t)cc * n * 16;
    float a0 = slice[(size_t)node * 16 + ln];  // self loop
    float a1 = 0.f, a2 = 0.f, a3 = 0.f;
    const int s = rowptr[node];
    const int e = rowptr[node + 1];
    int i = s;
    for (; i + 4 <= e; i += 4) {
        const int r0 = __builtin_nontemporal_load(&csr[i + 0]);
        const int r1 = __builtin_nontemporal_load(&csr[i + 1]);
        const int r2 = __builtin_nontemporal_load(&csr[i + 2]);
        const int r3 = __builtin_nontemporal_load(&csr[i + 3]);
        a0 += slice[(size_t)r0 * 16 + ln];
        a1 += slice[(size_t)r1 * 16 + ln];
        a2 += slice[(size_t)r2 * 16 + ln];
        a3 += slice[(size_t)r3 * 16 + ln];
    }
    for (; i < e; ++i) {
        const int r = __builtin_nontemporal_load(&csr[i]);
        a0 += slice[(size_t)r * 16 + ln];
    }
    const float acc = (a0 + a1) + (a2 + a3);
    const int f = cc * 16 + ln;
    float o = fmaf(acc, dinv[node], bias[f]);
    if (RELU) o = fmaxf(o, 0.f);
    __builtin_nontemporal_store(o, &out[(size_t)node * F + f]);
}

extern "C" void kernel_launch(void* const* d_in, const int* in_sizes, int n_in,
                              void* d_out, int out_size, void* d_ws, size_t ws_size,
                              hipStream_t stream) {
    const float* x  = (const float*)d_in[0];
    const int*   ei = (const int*)d_in[1];
    // d_in[2] = batch (unused in eval forward)
    const float* W1 = (const float*)d_in[3];
    const float* b1 = (const float*)d_in[4];
    const float* W2 = (const float*)d_in[5];
    const float* b2 = (const float*)d_in[6];
    const float* W3 = (const float*)d_in[7];
    const float* b3 = (const float*)d_in[8];
    float* out = (float*)d_out;

    const int N = in_sizes[0] / 128;
    const int E = in_sizes[1] / 2;
    const int* erow = ei;       // sources
    const int* ecol = ei + E;   // destinations

    // Workspace layout — round-1-proven footprint (55,200,768 B).
    char* ws = (char*)d_ws;
    auto alloc = [&](size_t bytes) {
        char* p = ws;
        ws += (bytes + 255) & ~(size_t)255;
        return p;
    };
    int*   deg    = (int*)alloc((size_t)N * 4);
    int*   rowptr = (int*)alloc((size_t)(N + 1) * 4);
    int*   cursor = (int*)alloc((size_t)N * 4);
    int*   csr    = (int*)alloc((size_t)E * 4);
    float* dinv   = (float*)alloc((size_t)N * 4);
    float* buf1   = (float*)alloc((size_t)N * 128 * 4);
    float* buf2   = (float*)alloc((size_t)N * 128 * 4);

    // Scan temporaries alias buf1 (dead until first GEMM writes it).
    int* local = (int*)buf1;
    int* bsums = local + N;
    int* boffs = bsums + 64;

    const int nb = (N + 1023) / 1024;  // scan2 assumes nb <= 64

    hipMemsetAsync(deg, 0, (size_t)N * 4, stream);
    count_kernel<<<(E + 255) / 256, 256, 0, stream>>>(ecol, deg, E, N);
    scan1_kernel<<<nb, 256, 0, stream>>>(deg, local, bsums, N);
    scan2_kernel<<<1, 64, 0, stream>>>(bsums, boffs, rowptr, nb, N);
    scan3_kernel<<<(N + 255) / 256, 256, 0, stream>>>(local, boffs, deg, rowptr, cursor, dinv, N);
    fill_kernel<<<(E + 255) / 256, 256, 0, stream>>>(erow, ecol, cursor, csr, E, N);

    const int ngroups = (N + 15) / 16;                 // 16 nodes per block
    const int grid128 = ngroups * 8;                   // NC=8, NSPLIT=1
    const int grid32  = ((ngroups + 3) / 4) * 8;       // NC=2, NSPLIT=4

    // Layer 1
    gemm_kernel<128><<<512, 256, 0, stream>>>(x, W1, dinv, buf1, N);
    agg_chunk_kernel<8, true><<<grid128, 256, 0, stream>>>(buf1, rowptr, csr, dinv, b1, buf2, N);

    // Layer 2
    gemm_kernel<128><<<512, 256, 0, stream>>>(buf2, W2, dinv, buf1, N);
    agg_chunk_kernel<8, true><<<grid128, 256, 0, stream>>>(buf1, rowptr, csr, dinv, b2, buf2, N);

    // Layer 3: logits (no relu), 32 classes -> d_out
    gemm_kernel<32><<<512, 256, 0, stream>>>(buf2, W3, dinv, buf1, N);
    agg_chunk_kernel<2, false><<<grid32, 256, 0, stream>>>(buf1, rowptr, csr, dinv, b3, out, N);
}

// Round 6
// 359.601 us; speedup vs baseline: 1.2308x; 1.2308x over previous
//
#include <hip/hip_runtime.h>
#include <math.h>

// ---------------------------------------------------------------------------
// 3-layer GCN forward.
//   1. deg count (int atomics over edge dst)
//   2. two-level exclusive scan -> rowptr + cursor (+ fused dinv)
//      (scan temporaries alias buf1, which is dead until the first GEMM)
//   3. CSR fill (scatter src ids by dst)
//   4. per layer: GEMM (h = X@W scaled by dinv[row], row-major, W from L2 —
//      no LDS so occupancy isn't capped) then row-major gather-aggregate
//      with 8-deep predicated unroll (8 independent 512B gathers in flight).
// ---------------------------------------------------------------------------

__global__ void count_kernel(const int* __restrict__ col, int* __restrict__ deg, int E, int n) {
    int e = blockIdx.x * blockDim.x + threadIdx.x;
    if (e < E) {
        int c = col[e];
        if ((unsigned)c < (unsigned)n) atomicAdd(&deg[c], 1);
    }
}

__global__ __launch_bounds__(256) void scan1_kernel(const int* __restrict__ deg,
                                                    int* __restrict__ local,
                                                    int* __restrict__ blocksums, int n) {
    __shared__ int wsum[4];
    const int t = threadIdx.x;
    const int lane = t & 63;
    const int wv = t >> 6;
    const int base = blockIdx.x * 1024 + t * 4;
    int a0 = (base + 0 < n) ? deg[base + 0] : 0;
    int a1 = (base + 1 < n) ? deg[base + 1] : 0;
    int a2 = (base + 2 < n) ? deg[base + 2] : 0;
    int a3 = (base + 3 < n) ? deg[base + 3] : 0;
    const int tot = a0 + a1 + a2 + a3;
    int incl = tot;
#pragma unroll
    for (int off = 1; off < 64; off <<= 1) {
        int u = __shfl_up(incl, off);
        if (lane >= off) incl += u;
    }
    if (lane == 63) wsum[wv] = incl;
    __syncthreads();
    int woff = 0;
#pragma unroll
    for (int w = 0; w < 4; ++w) woff += (w < wv) ? wsum[w] : 0;
    const int excl = woff + incl - tot;
    if (base + 0 < n) local[base + 0] = excl;
    if (base + 1 < n) local[base + 1] = excl + a0;
    if (base + 2 < n) local[base + 2] = excl + a0 + a1;
    if (base + 3 < n) local[base + 3] = excl + a0 + a1 + a2;
    if (t == 255) blocksums[blockIdx.x] = woff + incl;
}

__global__ void scan2_kernel(const int* __restrict__ blocksums, int* __restrict__ blockoff,
                             int* __restrict__ rowptr, int nb, int n) {
    const int lane = threadIdx.x;  // 64 threads
    int v = (lane < nb) ? blocksums[lane] : 0;
    int incl = v;
#pragma unroll
    for (int off = 1; off < 64; off <<= 1) {
        int u = __shfl_up(incl, off);
        if (lane >= off) incl += u;
    }
    if (lane < nb) blockoff[lane] = incl - v;
    if (lane == 63) rowptr[n] = incl;
}

__global__ void scan3_kernel(const int* __restrict__ local, const int* __restrict__ blockoff,
                             const int* __restrict__ deg, int* __restrict__ rowptr,
                             int* __restrict__ cursor, float* __restrict__ dinv, int n) {
    int i = blockIdx.x * blockDim.x + threadIdx.x;
    if (i < n) {
        const int v = local[i] + blockoff[i >> 10];
        rowptr[i] = v;
        cursor[i] = v;
        dinv[i] = rsqrtf((float)deg[i] + 1.0f);
    }
}

__global__ void fill_kernel(const int* __restrict__ row, const int* __restrict__ col,
                            int* __restrict__ cursor, int* __restrict__ csr, int E, int n) {
    int e = blockIdx.x * blockDim.x + threadIdx.x;
    if (e < E) {
        int c = col[e];
        int r = row[e];
        if ((unsigned)c < (unsigned)n && (unsigned)r < (unsigned)n) {
            int pos = atomicAdd(&cursor[c], 1);
            csr[pos] = r;
        }
    }
}

// h = X @ W (row r scaled by dinv[r]), row-major out.  No LDS: W is 64 KB and
// L2-resident; per half-wave the W quad loads are a coalesced 512 B stream,
// X loads are wave-uniform broadcasts. R=4 rows register-blocked per thread.
template <int OUT>
__global__ __launch_bounds__(256) void gemm_kernel(const float* __restrict__ X,
                                                   const float* __restrict__ W,
                                                   const float* __restrict__ dinv,
                                                   float* __restrict__ out, int n) {
    constexpr int CQ  = OUT / 4;        // column quads (32 or 8)
    constexpr int RG  = 256 / CQ;       // row-groups per block (8 or 32)
    constexpr int R   = 4;              // rows per thread
    constexpr int RPI = RG * R;         // rows per block (32 or 128)
    const int t = threadIdx.x;
    const int cq = t % CQ;
    const int rg = t / CQ;
    const float4* X4 = (const float4*)X;
    const float4* W4 = (const float4*)W;   // W4[k*CQ + cq] = W[k][4cq..4cq+3]

    const int r0 = blockIdx.x * RPI + rg * R;
    float4 acc[R];
#pragma unroll
    for (int r = 0; r < R; ++r) acc[r] = make_float4(0.f, 0.f, 0.f, 0.f);

    if (r0 + R <= n) {
#pragma unroll 4
        for (int k4 = 0; k4 < 32; ++k4) {
            float4 w0 = W4[(k4 * 4 + 0) * CQ + cq];
            float4 w1 = W4[(k4 * 4 + 1) * CQ + cq];
            float4 w2 = W4[(k4 * 4 + 2) * CQ + cq];
            float4 w3 = W4[(k4 * 4 + 3) * CQ + cq];
#pragma unroll
            for (int r = 0; r < R; ++r) {
                float4 xv = X4[(size_t)(r0 + r) * 32 + k4];
                acc[r].x = fmaf(xv.x, w0.x, acc[r].x);
                acc[r].x = fmaf(xv.y, w1.x, acc[r].x);
                acc[r].x = fmaf(xv.z, w2.x, acc[r].x);
                acc[r].x = fmaf(xv.w, w3.x, acc[r].x);
                acc[r].y = fmaf(xv.x, w0.y, acc[r].y);
                acc[r].y = fmaf(xv.y, w1.y, acc[r].y);
                acc[r].y = fmaf(xv.z, w2.y, acc[r].y);
                acc[r].y = fmaf(xv.w, w3.y, acc[r].y);
                acc[r].z = fmaf(xv.x, w0.z, acc[r].z);
                acc[r].z = fmaf(xv.y, w1.z, acc[r].z);
                acc[r].z = fmaf(xv.z, w2.z, acc[r].z);
                acc[r].z = fmaf(xv.w, w3.z, acc[r].z);
                acc[r].w = fmaf(xv.x, w0.w, acc[r].w);
                acc[r].w = fmaf(xv.y, w1.w, acc[r].w);
                acc[r].w = fmaf(xv.z, w2.w, acc[r].w);
                acc[r].w = fmaf(xv.w, w3.w, acc[r].w);
            }
        }
#pragma unroll
        for (int r = 0; r < R; ++r) {
            const float s = dinv[r0 + r];
            acc[r].x *= s; acc[r].y *= s; acc[r].z *= s; acc[r].w *= s;
            *(float4*)&out[(size_t)(r0 + r) * OUT + cq * 4] = acc[r];
        }
    } else if (r0 < n) {
        for (int r = 0; r < R; ++r) {
            const int row = r0 + r;
            if (row >= n) break;
            float4 a = make_float4(0.f, 0.f, 0.f, 0.f);
            for (int k4 = 0; k4 < 32; ++k4) {
                float4 xv = X4[(size_t)row * 32 + k4];
                float4 w0 = W4[(k4 * 4 + 0) * CQ + cq];
                float4 w1 = W4[(k4 * 4 + 1) * CQ + cq];
                float4 w2 = W4[(k4 * 4 + 2) * CQ + cq];
                float4 w3 = W4[(k4 * 4 + 3) * CQ + cq];
                a.x = fmaf(xv.x, w0.x, a.x); a.x = fmaf(xv.y, w1.x, a.x);
                a.x = fmaf(xv.z, w2.x, a.x); a.x = fmaf(xv.w, w3.x, a.x);
                a.y = fmaf(xv.x, w0.y, a.y); a.y = fmaf(xv.y, w1.y, a.y);
                a.y = fmaf(xv.z, w2.y, a.y); a.y = fmaf(xv.w, w3.y, a.y);
                a.z = fmaf(xv.x, w0.z, a.z); a.z = fmaf(xv.y, w1.z, a.z);
                a.z = fmaf(xv.z, w2.z, a.z); a.z = fmaf(xv.w, w3.z, a.z);
                a.w = fmaf(xv.x, w0.w, a.w); a.w = fmaf(xv.y, w1.w, a.w);
                a.w = fmaf(xv.z, w2.w, a.w); a.w = fmaf(xv.w, w3.w, a.w);
            }
            const float s = dinv[row];
            a.x *= s; a.y *= s; a.z *= s; a.w *= s;
            *(float4*)&out[(size_t)row * OUT + cq * 4] = a;
        }
    }
}

// out[c] = act( dinv[c] * (sum_{r in in(c)} hs[r] + hs[c]) + bias )
// Row-major gathers (512 B per instruction for F=128), 8-deep PREDICATED
// unroll: every iteration issues 8 independent index loads + 8 independent
// gathers (tail lanes gather a safe row and multiply by 0) -> deep MLP with
// no serial remainder loop.
template <int F, bool RELU>
__global__ __launch_bounds__(256) void agg_kernel(const float* __restrict__ hs,
                                                  const int* __restrict__ rowptr,
                                                  const int* __restrict__ csr,
                                                  const float* __restrict__ dinv,
                                                  const float* __restrict__ bias,
                                                  float* __restrict__ out, int n) {
    constexpr int LPN = F / 2;     // lanes per node (float2 per lane)
    constexpr int NPB = 256 / LPN; // nodes per block
    constexpr int F2  = F / 2;
    const int t = threadIdx.x;
    const int node = blockIdx.x * NPB + t / LPN;
    const int fo = t % LPN;        // float2 index within row
    if (node >= n) return;

    const float2* h2 = (const float2*)hs;
    float2 a0 = h2[(size_t)node * F2 + fo];  // self loop
    float ax[8], ay[8];
#pragma unroll
    for (int j = 0; j < 8; ++j) { ax[j] = 0.f; ay[j] = 0.f; }

    const int s = rowptr[node];
    const int e = rowptr[node + 1];
    for (int i = s; i < e; i += 8) {
        int   idx[8];
        float msk[8];
#pragma unroll
        for (int j = 0; j < 8; ++j) {
            const int k = i + j;
            const bool ok = (k < e);
            idx[j] = ok ? csr[k] : csr[s];
            msk[j] = ok ? 1.f : 0.f;
        }
#pragma unroll
        for (int j = 0; j < 8; ++j) {
            float2 v = h2[(size_t)idx[j] * F2 + fo];
            ax[j] = fmaf(v.x, msk[j], ax[j]);
            ay[j] = fmaf(v.y, msk[j], ay[j]);
        }
    }
    const float accx = a0.x + ((ax[0] + ax[1]) + (ax[2] + ax[3])) + ((ax[4] + ax[5]) + (ax[6] + ax[7]));
    const float accy = a0.y + ((ay[0] + ay[1]) + (ay[2] + ay[3])) + ((ay[4] + ay[5]) + (ay[6] + ay[7]));
    const float dc = dinv[node];
    const float2 b = *(const float2*)&bias[fo * 2];
    float ox = fmaf(accx, dc, b.x);
    float oy = fmaf(accy, dc, b.y);
    if (RELU) {
        ox = fmaxf(ox, 0.f);
        oy = fmaxf(oy, 0.f);
    }
    float2 res = {ox, oy};
    *(float2*)&out[(size_t)node * F + fo * 2] = res;
}

extern "C" void kernel_launch(void* const* d_in, const int* in_sizes, int n_in,
                              void* d_out, int out_size, void* d_ws, size_t ws_size,
                              hipStream_t stream) {
    const float* x  = (const float*)d_in[0];
    const int*   ei = (const int*)d_in[1];
    // d_in[2] = batch (unused in eval forward)
    const float* W1 = (const float*)d_in[3];
    const float* b1 = (const float*)d_in[4];
    const float* W2 = (const float*)d_in[5];
    const float* b2 = (const float*)d_in[6];
    const float* W3 = (const float*)d_in[7];
    const float* b3 = (const float*)d_in[8];
    float* out = (float*)d_out;

    const int N = in_sizes[0] / 128;
    const int E = in_sizes[1] / 2;
    const int* erow = ei;       // sources
    const int* ecol = ei + E;   // destinations

    // Workspace layout — round-1-proven footprint (55,200,768 B).
    char* ws = (char*)d_ws;
    auto alloc = [&](size_t bytes) {
        char* p = ws;
        ws += (bytes + 255) & ~(size_t)255;
        return p;
    };
    int*   deg    = (int*)alloc((size_t)N * 4);
    int*   rowptr = (int*)alloc((size_t)(N + 1) * 4);
    int*   cursor = (int*)alloc((size_t)N * 4);
    int*   csr    = (int*)alloc((size_t)E * 4);
    float* dinv   = (float*)alloc((size_t)N * 4);
    float* buf1   = (float*)alloc((size_t)N * 128 * 4);
    float* buf2   = (float*)alloc((size_t)N * 128 * 4);

    // Scan temporaries alias buf1 (dead until first GEMM writes it).
    int* local = (int*)buf1;
    int* bsums = local + N;
    int* boffs = bsums + 64;

    const int nb = (N + 1023) / 1024;  // scan2 assumes nb <= 64

    hipMemsetAsync(deg, 0, (size_t)N * 4, stream);
    count_kernel<<<(E + 255) / 256, 256, 0, stream>>>(ecol, deg, E, N);
    scan1_kernel<<<nb, 256, 0, stream>>>(deg, local, bsums, N);
    scan2_kernel<<<1, 64, 0, stream>>>(bsums, boffs, rowptr, nb, N);
    scan3_kernel<<<(N + 255) / 256, 256, 0, stream>>>(local, boffs, deg, rowptr, cursor, dinv, N);
    fill_kernel<<<(E + 255) / 256, 256, 0, stream>>>(erow, ecol, cursor, csr, E, N);

    const int g128 = (N + 31) / 32;    // gemm<128>: RPI=32
    const int g32  = (N + 127) / 128;  // gemm<32>:  RPI=128

    // Layer 1
    gemm_kernel<128><<<g128, 256, 0, stream>>>(x, W1, dinv, buf1, N);
    agg_kernel<128, true><<<(N + 3) / 4, 256, 0, stream>>>(buf1, rowptr, csr, dinv, b1, buf2, N);

    // Layer 2
    gemm_kernel<128><<<g128, 256, 0, stream>>>(buf2, W2, dinv, buf1, N);
    agg_kernel<128, true><<<(N + 3) / 4, 256, 0, stream>>>(buf1, rowptr, csr, dinv, b2, buf2, N);

    // Layer 3: logits (no relu), 32 classes -> d_out
    gemm_kernel<32><<<g32, 256, 0, stream>>>(buf2, W3, dinv, buf1, N);
    agg_kernel<32, false><<<(N + 15) / 16, 256, 0, stream>>>(buf1, rowptr, csr, dinv, b3, out, N);
}

// Round 7
// 331.656 us; speedup vs baseline: 1.3345x; 1.0843x over previous
//
#include <hip/hip_runtime.h>
#include <math.h>

// ---------------------------------------------------------------------------
// 3-layer GCN forward.
//   1. deg count (int atomics over edge dst)
//   2. two-level exclusive scan -> rowptr + cursor (+ fused dinv)
//      (scan temporaries alias buf1, which is dead until the first GEMM)
//   3. CSR fill (scatter src ids by dst)
//   4. per layer: GEMM (h = X@W scaled by dinv[row]; W column-half staged in
//      32KB LDS -> 5 blocks/CU) then row-major gather-aggregate (float4
//      lanes, 8-deep predicated unroll -> 8KB of gathers in flight per wave).
// ---------------------------------------------------------------------------

__global__ void count_kernel(const int* __restrict__ col, int* __restrict__ deg, int E, int n) {
    int e = blockIdx.x * blockDim.x + threadIdx.x;
    if (e < E) {
        int c = col[e];
        if ((unsigned)c < (unsigned)n) atomicAdd(&deg[c], 1);
    }
}

__global__ __launch_bounds__(256) void scan1_kernel(const int* __restrict__ deg,
                                                    int* __restrict__ local,
                                                    int* __restrict__ blocksums, int n) {
    __shared__ int wsum[4];
    const int t = threadIdx.x;
    const int lane = t & 63;
    const int wv = t >> 6;
    const int base = blockIdx.x * 1024 + t * 4;
    int a0 = (base + 0 < n) ? deg[base + 0] : 0;
    int a1 = (base + 1 < n) ? deg[base + 1] : 0;
    int a2 = (base + 2 < n) ? deg[base + 2] : 0;
    int a3 = (base + 3 < n) ? deg[base + 3] : 0;
    const int tot = a0 + a1 + a2 + a3;
    int incl = tot;
#pragma unroll
    for (int off = 1; off < 64; off <<= 1) {
        int u = __shfl_up(incl, off);
        if (lane >= off) incl += u;
    }
    if (lane == 63) wsum[wv] = incl;
    __syncthreads();
    int woff = 0;
#pragma unroll
    for (int w = 0; w < 4; ++w) woff += (w < wv) ? wsum[w] : 0;
    const int excl = woff + incl - tot;
    if (base + 0 < n) local[base + 0] = excl;
    if (base + 1 < n) local[base + 1] = excl + a0;
    if (base + 2 < n) local[base + 2] = excl + a0 + a1;
    if (base + 3 < n) local[base + 3] = excl + a0 + a1 + a2;
    if (t == 255) blocksums[blockIdx.x] = woff + incl;
}

__global__ void scan2_kernel(const int* __restrict__ blocksums, int* __restrict__ blockoff,
                             int* __restrict__ rowptr, int nb, int n) {
    const int lane = threadIdx.x;  // 64 threads
    int v = (lane < nb) ? blocksums[lane] : 0;
    int incl = v;
#pragma unroll
    for (int off = 1; off < 64; off <<= 1) {
        int u = __shfl_up(incl, off);
        if (lane >= off) incl += u;
    }
    if (lane < nb) blockoff[lane] = incl - v;
    if (lane == 63) rowptr[n] = incl;
}

__global__ void scan3_kernel(const int* __restrict__ local, const int* __restrict__ blockoff,
                             const int* __restrict__ deg, int* __restrict__ rowptr,
                             int* __restrict__ cursor, float* __restrict__ dinv, int n) {
    int i = blockIdx.x * blockDim.x + threadIdx.x;
    if (i < n) {
        const int v = local[i] + blockoff[i >> 10];
        rowptr[i] = v;
        cursor[i] = v;
        dinv[i] = rsqrtf((float)deg[i] + 1.0f);
    }
}

__global__ void fill_kernel(const int* __restrict__ row, const int* __restrict__ col,
                            int* __restrict__ cursor, int* __restrict__ csr, int E, int n) {
    int e = blockIdx.x * blockDim.x + threadIdx.x;
    if (e < E) {
        int c = col[e];
        int r = row[e];
        if ((unsigned)c < (unsigned)n && (unsigned)r < (unsigned)n) {
            int pos = atomicAdd(&cursor[c], 1);
            csr[pos] = r;
        }
    }
}

// h[:, c0:c0+COLS] = X @ W[:, c0:c0+COLS], row r scaled by dinv[r].
// W column-slab staged in LDS (COLS=64 -> 32KB -> 5 blocks/CU). R=4 rows
// register-blocked per thread: 16 LDS floats feed 64 FMAs.
template <int OUT, int COLS>
__global__ __launch_bounds__(256) void gemm_kernel(const float* __restrict__ X,
                                                   const float* __restrict__ W,
                                                   const float* __restrict__ dinv,
                                                   float* __restrict__ out, int n) {
    constexpr int NSLAB = OUT / COLS;
    constexpr int CQ  = COLS / 4;       // column quads per slab (16 or 8)
    constexpr int RG  = 256 / CQ;       // row-groups per block (16 or 32)
    constexpr int R   = 4;              // rows per thread
    constexpr int RPI = RG * R;         // rows per block (64 or 128)
    __shared__ float Wl[128 * COLS];

    const int t = threadIdx.x;
    const int c0 = (int)(blockIdx.x % NSLAB) * COLS;
    const int rowblk = blockIdx.x / NSLAB;

    // Stage the column slab: Wl[k][0:COLS] = W[k][c0:c0+COLS], float4 loads.
    for (int i = t; i < 128 * CQ; i += 256) {
        const int k  = i / CQ;
        const int cc = i % CQ;
        ((float4*)Wl)[i] = *(const float4*)&W[(size_t)k * OUT + c0 + cc * 4];
    }
    __syncthreads();

    const int cq = t % CQ;
    const int rg = t / CQ;
    const float4* X4 = (const float4*)X;

    const int r0 = rowblk * RPI + rg * R;
    float4 acc[R];
#pragma unroll
    for (int r = 0; r < R; ++r) acc[r] = make_float4(0.f, 0.f, 0.f, 0.f);

    if (r0 + R <= n) {
#pragma unroll 4
        for (int k4 = 0; k4 < 32; ++k4) {
            const float* wp = &Wl[k4 * 4 * COLS + cq * 4];
            float4 w0 = *(const float4*)(wp);
            float4 w1 = *(const float4*)(wp + COLS);
            float4 w2 = *(const float4*)(wp + 2 * COLS);
            float4 w3 = *(const float4*)(wp + 3 * COLS);
#pragma unroll
            for (int r = 0; r < R; ++r) {
                float4 xv = X4[(size_t)(r0 + r) * 32 + k4];
                acc[r].x = fmaf(xv.x, w0.x, acc[r].x);
                acc[r].x = fmaf(xv.y, w1.x, acc[r].x);
                acc[r].x = fmaf(xv.z, w2.x, acc[r].x);
                acc[r].x = fmaf(xv.w, w3.x, acc[r].x);
                acc[r].y = fmaf(xv.x, w0.y, acc[r].y);
                acc[r].y = fmaf(xv.y, w1.y, acc[r].y);
                acc[r].y = fmaf(xv.z, w2.y, acc[r].y);
                acc[r].y = fmaf(xv.w, w3.y, acc[r].y);
                acc[r].z = fmaf(xv.x, w0.z, acc[r].z);
                acc[r].z = fmaf(xv.y, w1.z, acc[r].z);
                acc[r].z = fmaf(xv.z, w2.z, acc[r].z);
                acc[r].z = fmaf(xv.w, w3.z, acc[r].z);
                acc[r].w = fmaf(xv.x, w0.w, acc[r].w);
                acc[r].w = fmaf(xv.y, w1.w, acc[r].w);
                acc[r].w = fmaf(xv.z, w2.w, acc[r].w);
                acc[r].w = fmaf(xv.w, w3.w, acc[r].w);
            }
        }
#pragma unroll
        for (int r = 0; r < R; ++r) {
            const float s = dinv[r0 + r];
            acc[r].x *= s; acc[r].y *= s; acc[r].z *= s; acc[r].w *= s;
            *(float4*)&out[(size_t)(r0 + r) * OUT + c0 + cq * 4] = acc[r];
        }
    } else if (r0 < n) {
        for (int r = 0; r < R; ++r) {
            const int row = r0 + r;
            if (row >= n) break;
            float4 a = make_float4(0.f, 0.f, 0.f, 0.f);
            for (int k4 = 0; k4 < 32; ++k4) {
                float4 xv = X4[(size_t)row * 32 + k4];
                const float* wp = &Wl[k4 * 4 * COLS + cq * 4];
                float4 w0 = *(const float4*)(wp);
                float4 w1 = *(const float4*)(wp + COLS);
                float4 w2 = *(const float4*)(wp + 2 * COLS);
                float4 w3 = *(const float4*)(wp + 3 * COLS);
                a.x = fmaf(xv.x, w0.x, a.x); a.x = fmaf(xv.y, w1.x, a.x);
                a.x = fmaf(xv.z, w2.x, a.x); a.x = fmaf(xv.w, w3.x, a.x);
                a.y = fmaf(xv.x, w0.y, a.y); a.y = fmaf(xv.y, w1.y, a.y);
                a.y = fmaf(xv.z, w2.y, a.y); a.y = fmaf(xv.w, w3.y, a.y);
                a.z = fmaf(xv.x, w0.z, a.z); a.z = fmaf(xv.y, w1.z, a.z);
                a.z = fmaf(xv.z, w2.z, a.z); a.z = fmaf(xv.w, w3.z, a.z);
                a.w = fmaf(xv.x, w0.w, a.w); a.w = fmaf(xv.y, w1.w, a.w);
                a.w = fmaf(xv.z, w2.w, a.w); a.w = fmaf(xv.w, w3.w, a.w);
            }
            const float s = dinv[row];
            a.x *= s; a.y *= s; a.z *= s; a.w *= s;
            *(float4*)&out[(size_t)row * OUT + c0 + cq * 4] = a;
        }
    }
}

// out[c] = act( dinv[c] * (sum_{r in in(c)} hs[r] + hs[c]) + bias )
// float4 per lane (F=128: 32 lanes/node -> 2 nodes/wave; each gather
// instruction moves 2x512B), 8-deep predicated unroll -> 8KB in flight/wave.
template <int F, bool RELU>
__global__ __launch_bounds__(256) void agg_kernel(const float* __restrict__ hs,
                                                  const int* __restrict__ rowptr,
                                                  const int* __restrict__ csr,
                                                  const float* __restrict__ dinv,
                                                  const float* __restrict__ bias,
                                                  float* __restrict__ out, int n) {
    constexpr int LPN = F / 4;     // lanes per node (float4 per lane)
    constexpr int NPB = 256 / LPN; // nodes per block
    constexpr int F4  = F / 4;
    const int t = threadIdx.x;
    const int node = blockIdx.x * NPB + t / LPN;
    const int fo = t % LPN;        // float4 index within row
    if (node >= n) return;

    const float4* h4 = (const float4*)hs;
    float4 self = h4[(size_t)node * F4 + fo];  // self loop
    float4 a[8];
#pragma unroll
    for (int j = 0; j < 8; ++j) a[j] = make_float4(0.f, 0.f, 0.f, 0.f);

    const int s = rowptr[node];
    const int e = rowptr[node + 1];
    for (int i = s; i < e; i += 8) {
        int   idx[8];
        float msk[8];
#pragma unroll
        for (int j = 0; j < 8; ++j) {
            const int k = i + j;
            const int kc = (k < e) ? k : (e - 1);
            idx[j] = csr[kc];
            msk[j] = (k < e) ? 1.f : 0.f;
        }
#pragma unroll
        for (int j = 0; j < 8; ++j) {
            float4 v = h4[(size_t)idx[j] * F4 + fo];
            a[j].x = fmaf(v.x, msk[j], a[j].x);
            a[j].y = fmaf(v.y, msk[j], a[j].y);
            a[j].z = fmaf(v.z, msk[j], a[j].z);
            a[j].w = fmaf(v.w, msk[j], a[j].w);
        }
    }
    float accx = self.x + ((a[0].x + a[1].x) + (a[2].x + a[3].x)) + ((a[4].x + a[5].x) + (a[6].x + a[7].x));
    float accy = self.y + ((a[0].y + a[1].y) + (a[2].y + a[3].y)) + ((a[4].y + a[5].y) + (a[6].y + a[7].y));
    float accz = self.z + ((a[0].z + a[1].z) + (a[2].z + a[3].z)) + ((a[4].z + a[5].z) + (a[6].z + a[7].z));
    float accw = self.w + ((a[0].w + a[1].w) + (a[2].w + a[3].w)) + ((a[4].w + a[5].w) + (a[6].w + a[7].w));
    const float dc = dinv[node];
    const float4 b = *(const float4*)&bias[fo * 4];
    float ox = fmaf(accx, dc, b.x);
    float oy = fmaf(accy, dc, b.y);
    float oz = fmaf(accz, dc, b.z);
    float ow = fmaf(accw, dc, b.w);
    if (RELU) {
        ox = fmaxf(ox, 0.f); oy = fmaxf(oy, 0.f);
        oz = fmaxf(oz, 0.f); ow = fmaxf(ow, 0.f);
    }
    float4 res = {ox, oy, oz, ow};
    *(float4*)&out[(size_t)node * F + fo * 4] = res;
}

extern "C" void kernel_launch(void* const* d_in, const int* in_sizes, int n_in,
                              void* d_out, int out_size, void* d_ws, size_t ws_size,
                              hipStream_t stream) {
    const float* x  = (const float*)d_in[0];
    const int*   ei = (const int*)d_in[1];
    // d_in[2] = batch (unused in eval forward)
    const float* W1 = (const float*)d_in[3];
    const float* b1 = (const float*)d_in[4];
    const float* W2 = (const float*)d_in[5];
    const float* b2 = (const float*)d_in[6];
    const float* W3 = (const float*)d_in[7];
    const float* b3 = (const float*)d_in[8];
    float* out = (float*)d_out;

    const int N = in_sizes[0] / 128;
    const int E = in_sizes[1] / 2;
    const int* erow = ei;       // sources
    const int* ecol = ei + E;   // destinations

    // Workspace layout — round-1-proven footprint (55,200,768 B).
    char* ws = (char*)d_ws;
    auto alloc = [&](size_t bytes) {
        char* p = ws;
        ws += (bytes + 255) & ~(size_t)255;
        return p;
    };
    int*   deg    = (int*)alloc((size_t)N * 4);
    int*   rowptr = (int*)alloc((size_t)(N + 1) * 4);
    int*   cursor = (int*)alloc((size_t)N * 4);
    int*   csr    = (int*)alloc((size_t)E * 4);
    float* dinv   = (float*)alloc((size_t)N * 4);
    float* buf1   = (float*)alloc((size_t)N * 128 * 4);
    float* buf2   = (float*)alloc((size_t)N * 128 * 4);

    // Scan temporaries alias buf1 (dead until first GEMM writes it).
    int* local = (int*)buf1;
    int* bsums = local + N;
    int* boffs = bsums + 64;

    const int nb = (N + 1023) / 1024;  // scan2 assumes nb <= 64

    hipMemsetAsync(deg, 0, (size_t)N * 4, stream);
    count_kernel<<<(E + 255) / 256, 256, 0, stream>>>(ecol, deg, E, N);
    scan1_kernel<<<nb, 256, 0, stream>>>(deg, local, bsums, N);
    scan2_kernel<<<1, 64, 0, stream>>>(bsums, boffs, rowptr, nb, N);
    scan3_kernel<<<(N + 255) / 256, 256, 0, stream>>>(local, boffs, deg, rowptr, cursor, dinv, N);
    fill_kernel<<<(E + 255) / 256, 256, 0, stream>>>(erow, ecol, cursor, csr, E, N);

    const int g128 = ((N + 63) / 64) * 2;   // gemm<128,64>: RPI=64, 2 slabs
    const int g32  = (N + 127) / 128;       // gemm<32,32>:  RPI=128, 1 slab

    // Layer 1
    gemm_kernel<128, 64><<<g128, 256, 0, stream>>>(x, W1, dinv, buf1, N);
    agg_kernel<128, true><<<(N + 7) / 8, 256, 0, stream>>>(buf1, rowptr, csr, dinv, b1, buf2, N);

    // Layer 2
    gemm_kernel<128, 64><<<g128, 256, 0, stream>>>(buf2, W2, dinv, buf1, N);
    agg_kernel<128, true><<<(N + 7) / 8, 256, 0, stream>>>(buf1, rowptr, csr, dinv, b2, buf2, N);

    // Layer 3: logits (no relu), 32 classes -> d_out
    gemm_kernel<32, 32><<<g32, 256, 0, stream>>>(buf2, W3, dinv, buf1, N);
    agg_kernel<32, false><<<(N + 31) / 32, 256, 0, stream>>>(buf1, rowptr, csr, dinv, b3, out, N);
}

// Round 8
// 316.873 us; speedup vs baseline: 1.3967x; 1.0467x over previous
//
#include <hip/hip_runtime.h>
#include <math.h>

// ---------------------------------------------------------------------------
// 3-layer GCN forward.
//   1. deg count — XCD-partitioned by dst range (blockIdx%8 -> XCD; each
//      partition's deg slice is private to one L2 -> no cross-XCD line bounce)
//   2. two-level exclusive scan -> rowptr + cursor (+ fused dinv)
//      (scan temporaries alias buf1, which is dead until the first GEMM)
//   3. CSR fill — same dst-range partitioning: cursor atomics and csr writes
//      stay in one XCD's L2, lines accumulate ~16 writes before eviction
//   4. per layer: GEMM (W column-slab in 32KB LDS, R=4 register blocking)
//      then row-major gather-aggregate (float4 lanes, 8-deep pred. unroll).
// ---------------------------------------------------------------------------

__global__ __launch_bounds__(256) void count_part_kernel(const int* __restrict__ col,
                                                         int* __restrict__ deg, int E, int n) {
    const int part = blockIdx.x & 7;
    const int nb = gridDim.x >> 3;
    const int chunk = blockIdx.x >> 3;
    const int lo = (int)(((long long)part * n) >> 3);
    const int hi = (int)(((long long)(part + 1) * n) >> 3);
    for (int e = chunk * 256 + threadIdx.x; e < E; e += nb * 256) {
        const int c = col[e];
        if (c >= lo && c < hi) atomicAdd(&deg[c], 1);
    }
}

__global__ __launch_bounds__(256) void scan1_kernel(const int* __restrict__ deg,
                                                    int* __restrict__ local,
                                                    int* __restrict__ blocksums, int n) {
    __shared__ int wsum[4];
    const int t = threadIdx.x;
    const int lane = t & 63;
    const int wv = t >> 6;
    const int base = blockIdx.x * 1024 + t * 4;
    int a0 = (base + 0 < n) ? deg[base + 0] : 0;
    int a1 = (base + 1 < n) ? deg[base + 1] : 0;
    int a2 = (base + 2 < n) ? deg[base + 2] : 0;
    int a3 = (base + 3 < n) ? deg[base + 3] : 0;
    const int tot = a0 + a1 + a2 + a3;
    int incl = tot;
#pragma unroll
    for (int off = 1; off < 64; off <<= 1) {
        int u = __shfl_up(incl, off);
        if (lane >= off) incl += u;
    }
    if (lane == 63) wsum[wv] = incl;
    __syncthreads();
    int woff = 0;
#pragma unroll
    for (int w = 0; w < 4; ++w) woff += (w < wv) ? wsum[w] : 0;
    const int excl = woff + incl - tot;
    if (base + 0 < n) local[base + 0] = excl;
    if (base + 1 < n) local[base + 1] = excl + a0;
    if (base + 2 < n) local[base + 2] = excl + a0 + a1;
    if (base + 3 < n) local[base + 3] = excl + a0 + a1 + a2;
    if (t == 255) blocksums[blockIdx.x] = woff + incl;
}

__global__ void scan2_kernel(const int* __restrict__ blocksums, int* __restrict__ blockoff,
                             int* __restrict__ rowptr, int nb, int n) {
    const int lane = threadIdx.x;  // 64 threads
    int v = (lane < nb) ? blocksums[lane] : 0;
    int incl = v;
#pragma unroll
    for (int off = 1; off < 64; off <<= 1) {
        int u = __shfl_up(incl, off);
        if (lane >= off) incl += u;
    }
    if (lane < nb) blockoff[lane] = incl - v;
    if (lane == 63) rowptr[n] = incl;
}

__global__ void scan3_kernel(const int* __restrict__ local, const int* __restrict__ blockoff,
                             const int* __restrict__ deg, int* __restrict__ rowptr,
                             int* __restrict__ cursor, float* __restrict__ dinv, int n) {
    int i = blockIdx.x * blockDim.x + threadIdx.x;
    if (i < n) {
        const int v = local[i] + blockoff[i >> 10];
        rowptr[i] = v;
        cursor[i] = v;
        dinv[i] = rsqrtf((float)deg[i] + 1.0f);
    }
}

__global__ __launch_bounds__(256) void fill_part_kernel(const int* __restrict__ row,
                                                        const int* __restrict__ col,
                                                        int* __restrict__ cursor,
                                                        int* __restrict__ csr, int E, int n) {
    const int part = blockIdx.x & 7;
    const int nb = gridDim.x >> 3;
    const int chunk = blockIdx.x >> 3;
    const int lo = (int)(((long long)part * n) >> 3);
    const int hi = (int)(((long long)(part + 1) * n) >> 3);
    for (int e = chunk * 256 + threadIdx.x; e < E; e += nb * 256) {
        const int c = col[e];
        if (c >= lo && c < hi) {
            const int r = row[e];
            if ((unsigned)r < (unsigned)n) {
                const int pos = atomicAdd(&cursor[c], 1);
                csr[pos] = r;
            }
        }
    }
}

// h[:, c0:c0+COLS] = X @ W[:, c0:c0+COLS], row r scaled by dinv[r].
// W column-slab staged in LDS (COLS=64 -> 32KB -> 5 blocks/CU). R=4 rows
// register-blocked per thread: 16 LDS floats feed 64 FMAs.
template <int OUT, int COLS>
__global__ __launch_bounds__(256) void gemm_kernel(const float* __restrict__ X,
                                                   const float* __restrict__ W,
                                                   const float* __restrict__ dinv,
                                                   float* __restrict__ out, int n) {
    constexpr int NSLAB = OUT / COLS;
    constexpr int CQ  = COLS / 4;
    constexpr int RG  = 256 / CQ;
    constexpr int R   = 4;
    constexpr int RPI = RG * R;
    __shared__ float Wl[128 * COLS];

    const int t = threadIdx.x;
    const int c0 = (int)(blockIdx.x % NSLAB) * COLS;
    const int rowblk = blockIdx.x / NSLAB;

    for (int i = t; i < 128 * CQ; i += 256) {
        const int k  = i / CQ;
        const int cc = i % CQ;
        ((float4*)Wl)[i] = *(const float4*)&W[(size_t)k * OUT + c0 + cc * 4];
    }
    __syncthreads();

    const int cq = t % CQ;
    const int rg = t / CQ;
    const float4* X4 = (const float4*)X;

    const int r0 = rowblk * RPI + rg * R;
    float4 acc[R];
#pragma unroll
    for (int r = 0; r < R; ++r) acc[r] = make_float4(0.f, 0.f, 0.f, 0.f);

    if (r0 + R <= n) {
#pragma unroll 4
        for (int k4 = 0; k4 < 32; ++k4) {
            const float* wp = &Wl[k4 * 4 * COLS + cq * 4];
            float4 w0 = *(const float4*)(wp);
            float4 w1 = *(const float4*)(wp + COLS);
            float4 w2 = *(const float4*)(wp + 2 * COLS);
            float4 w3 = *(const float4*)(wp + 3 * COLS);
#pragma unroll
            for (int r = 0; r < R; ++r) {
                float4 xv = X4[(size_t)(r0 + r) * 32 + k4];
                acc[r].x = fmaf(xv.x, w0.x, acc[r].x);
                acc[r].x = fmaf(xv.y, w1.x, acc[r].x);
                acc[r].x = fmaf(xv.z, w2.x, acc[r].x);
                acc[r].x = fmaf(xv.w, w3.x, acc[r].x);
                acc[r].y = fmaf(xv.x, w0.y, acc[r].y);
                acc[r].y = fmaf(xv.y, w1.y, acc[r].y);
                acc[r].y = fmaf(xv.z, w2.y, acc[r].y);
                acc[r].y = fmaf(xv.w, w3.y, acc[r].y);
                acc[r].z = fmaf(xv.x, w0.z, acc[r].z);
                acc[r].z = fmaf(xv.y, w1.z, acc[r].z);
                acc[r].z = fmaf(xv.z, w2.z, acc[r].z);
                acc[r].z = fmaf(xv.w, w3.z, acc[r].z);
                acc[r].w = fmaf(xv.x, w0.w, acc[r].w);
                acc[r].w = fmaf(xv.y, w1.w, acc[r].w);
                acc[r].w = fmaf(xv.z, w2.w, acc[r].w);
                acc[r].w = fmaf(xv.w, w3.w, acc[r].w);
            }
        }
#pragma unroll
        for (int r = 0; r < R; ++r) {
            const float s = dinv[r0 + r];
            acc[r].x *= s; acc[r].y *= s; acc[r].z *= s; acc[r].w *= s;
            *(float4*)&out[(size_t)(r0 + r) * OUT + c0 + cq * 4] = acc[r];
        }
    } else if (r0 < n) {
        for (int r = 0; r < R; ++r) {
            const int row = r0 + r;
            if (row >= n) break;
            float4 a = make_float4(0.f, 0.f, 0.f, 0.f);
            for (int k4 = 0; k4 < 32; ++k4) {
                float4 xv = X4[(size_t)row * 32 + k4];
                const float* wp = &Wl[k4 * 4 * COLS + cq * 4];
                float4 w0 = *(const float4*)(wp);
                float4 w1 = *(const float4*)(wp + COLS);
                float4 w2 = *(const float4*)(wp + 2 * COLS);
                float4 w3 = *(const float4*)(wp + 3 * COLS);
                a.x = fmaf(xv.x, w0.x, a.x); a.x = fmaf(xv.y, w1.x, a.x);
                a.x = fmaf(xv.z, w2.x, a.x); a.x = fmaf(xv.w, w3.x, a.x);
                a.y = fmaf(xv.x, w0.y, a.y); a.y = fmaf(xv.y, w1.y, a.y);
                a.y = fmaf(xv.z, w2.y, a.y); a.y = fmaf(xv.w, w3.y, a.y);
                a.z = fmaf(xv.x, w0.z, a.z); a.z = fmaf(xv.y, w1.z, a.z);
                a.z = fmaf(xv.z, w2.z, a.z); a.z = fmaf(xv.w, w3.z, a.z);
                a.w = fmaf(xv.x, w0.w, a.w); a.w = fmaf(xv.y, w1.w, a.w);
                a.w = fmaf(xv.z, w2.w, a.w); a.w = fmaf(xv.w, w3.w, a.w);
            }
            const float s = dinv[row];
            a.x *= s; a.y *= s; a.z *= s; a.w *= s;
            *(float4*)&out[(size_t)row * OUT + c0 + cq * 4] = a;
        }
    }
}

// out[c] = act( dinv[c] * (sum_{r in in(c)} hs[r] + hs[c]) + bias )
// float4 per lane, 8-deep predicated unroll -> 8KB of gathers in flight/wave.
template <int F, bool RELU>
__global__ __launch_bounds__(256) void agg_kernel(const float* __restrict__ hs,
                                                  const int* __restrict__ rowptr,
                                                  const int* __restrict__ csr,
                                                  const float* __restrict__ dinv,
                                                  const float* __restrict__ bias,
                                                  float* __restrict__ out, int n) {
    constexpr int LPN = F / 4;
    constexpr int NPB = 256 / LPN;
    constexpr int F4  = F / 4;
    const int t = threadIdx.x;
    const int node = blockIdx.x * NPB + t / LPN;
    const int fo = t % LPN;
    if (node >= n) return;

    const float4* h4 = (const float4*)hs;
    float4 self = h4[(size_t)node * F4 + fo];
    float4 a[8];
#pragma unroll
    for (int j = 0; j < 8; ++j) a[j] = make_float4(0.f, 0.f, 0.f, 0.f);

    const int s = rowptr[node];
    const int e = rowptr[node + 1];
    for (int i = s; i < e; i += 8) {
        int   idx[8];
        float msk[8];
#pragma unroll
        for (int j = 0; j < 8; ++j) {
            const int k = i + j;
            const int kc = (k < e) ? k : (e - 1);
            idx[j] = csr[kc];
            msk[j] = (k < e) ? 1.f : 0.f;
        }
#pragma unroll
        for (int j = 0; j < 8; ++j) {
            float4 v = h4[(size_t)idx[j] * F4 + fo];
            a[j].x = fmaf(v.x, msk[j], a[j].x);
            a[j].y = fmaf(v.y, msk[j], a[j].y);
            a[j].z = fmaf(v.z, msk[j], a[j].z);
            a[j].w = fmaf(v.w, msk[j], a[j].w);
        }
    }
    float accx = self.x + ((a[0].x + a[1].x) + (a[2].x + a[3].x)) + ((a[4].x + a[5].x) + (a[6].x + a[7].x));
    float accy = self.y + ((a[0].y + a[1].y) + (a[2].y + a[3].y)) + ((a[4].y + a[5].y) + (a[6].y + a[7].y));
    float accz = self.z + ((a[0].z + a[1].z) + (a[2].z + a[3].z)) + ((a[4].z + a[5].z) + (a[6].z + a[7].z));
    float accw = self.w + ((a[0].w + a[1].w) + (a[2].w + a[3].w)) + ((a[4].w + a[5].w) + (a[6].w + a[7].w));
    const float dc = dinv[node];
    const float4 b = *(const float4*)&bias[fo * 4];
    float ox = fmaf(accx, dc, b.x);
    float oy = fmaf(accy, dc, b.y);
    float oz = fmaf(accz, dc, b.z);
    float ow = fmaf(accw, dc, b.w);
    if (RELU) {
        ox = fmaxf(ox, 0.f); oy = fmaxf(oy, 0.f);
        oz = fmaxf(oz, 0.f); ow = fmaxf(ow, 0.f);
    }
    float4 res = {ox, oy, oz, ow};
    *(float4*)&out[(size_t)node * F + fo * 4] = res;
}

extern "C" void kernel_launch(void* const* d_in, const int* in_sizes, int n_in,
                              void* d_out, int out_size, void* d_ws, size_t ws_size,
                              hipStream_t stream) {
    const float* x  = (const float*)d_in[0];
    const int*   ei = (const int*)d_in[1];
    // d_in[2] = batch (unused in eval forward)
    const float* W1 = (const float*)d_in[3];
    const float* b1 = (const float*)d_in[4];
    const float* W2 = (const float*)d_in[5];
    const float* b2 = (const float*)d_in[6];
    const float* W3 = (const float*)d_in[7];
    const float* b3 = (const float*)d_in[8];
    float* out = (float*)d_out;

    const int N = in_sizes[0] / 128;
    const int E = in_sizes[1] / 2;
    const int* erow = ei;       // sources
    const int* ecol = ei + E;   // destinations

    // Workspace layout — round-1-proven footprint (55,200,768 B).
    char* ws = (char*)d_ws;
    auto alloc = [&](size_t bytes) {
        char* p = ws;
        ws += (bytes + 255) & ~(size_t)255;
        return p;
    };
    int*   deg    = (int*)alloc((size_t)N * 4);
    int*   rowptr = (int*)alloc((size_t)(N + 1) * 4);
    int*   cursor = (int*)alloc((size_t)N * 4);
    int*   csr    = (int*)alloc((size_t)E * 4);
    float* dinv   = (float*)alloc((size_t)N * 4);
    float* buf1   = (float*)alloc((size_t)N * 128 * 4);
    float* buf2   = (float*)alloc((size_t)N * 128 * 4);

    // Scan temporaries alias buf1 (dead until first GEMM writes it).
    int* local = (int*)buf1;
    int* bsums = local + N;
    int* boffs = bsums + 64;

    const int nb = (N + 1023) / 1024;  // scan2 assumes nb <= 64

    hipMemsetAsync(deg, 0, (size_t)N * 4, stream);
    count_part_kernel<<<8 * 128, 256, 0, stream>>>(ecol, deg, E, N);
    scan1_kernel<<<nb, 256, 0, stream>>>(deg, local, bsums, N);
    scan2_kernel<<<1, 64, 0, stream>>>(bsums, boffs, rowptr, nb, N);
    scan3_kernel<<<(N + 255) / 256, 256, 0, stream>>>(local, boffs, deg, rowptr, cursor, dinv, N);
    fill_part_kernel<<<8 * 128, 256, 0, stream>>>(erow, ecol, cursor, csr, E, N);

    const int g128 = ((N + 63) / 64) * 2;   // gemm<128,64>: RPI=64, 2 slabs
    const int g32  = (N + 127) / 128;       // gemm<32,32>:  RPI=128, 1 slab

    // Layer 1
    gemm_kernel<128, 64><<<g128, 256, 0, stream>>>(x, W1, dinv, buf1, N);
    agg_kernel<128, true><<<(N + 7) / 8, 256, 0, stream>>>(buf1, rowptr, csr, dinv, b1, buf2, N);

    // Layer 2
    gemm_kernel<128, 64><<<g128, 256, 0, stream>>>(buf2, W2, dinv, buf1, N);
    agg_kernel<128, true><<<(N + 7) / 8, 256, 0, stream>>>(buf1, rowptr, csr, dinv, b2, buf2, N);

    // Layer 3: logits (no relu), 32 classes -> d_out
    gemm_kernel<32, 32><<<g32, 256, 0, stream>>>(buf2, W3, dinv, buf1, N);
    agg_kernel<32, false><<<(N + 31) / 32, 256, 0, stream>>>(buf1, rowptr, csr, dinv, b3, out, N);
}

// Round 9
// 287.304 us; speedup vs baseline: 1.5405x; 1.1029x over previous
//
#include <hip/hip_runtime.h>
#include <math.h>

// ---------------------------------------------------------------------------
// 3-layer GCN forward.
//   1. deg count — XCD-partitioned by dst range
//   2. two-level exclusive scan -> rowptr + cursor (+ fused dinv)
//      (scan temporaries alias buf1, dead until the first GEMM)
//   3. CSR fill — XCD-partitioned by dst range
//   4. layers 1-2: GEMM (W slab in 32KB LDS, R=4 reg blocking) writing
//      CHUNK-MAJOR [8][N][16]; then XCD-local chunked aggregate: block b owns
//      chunk b%8 -> its XCD's L2-resident 3.2MB slice; 4 lanes x float4 per
//      node, 8-deep predicated unroll (8KB in flight/wave). agg writes
//      row-major for the next GEMM.
//      layer 3: row-major GEMM<32> + plain float4 agg (R8 structure).
// ---------------------------------------------------------------------------

__global__ __launch_bounds__(256) void count_part_kernel(const int* __restrict__ col,
                                                         int* __restrict__ deg, int E, int n) {
    const int part = blockIdx.x & 7;
    const int nb = gridDim.x >> 3;
    const int chunk = blockIdx.x >> 3;
    const int lo = (int)(((long long)part * n) >> 3);
    const int hi = (int)(((long long)(part + 1) * n) >> 3);
    for (int e = chunk * 256 + threadIdx.x; e < E; e += nb * 256) {
        const int c = col[e];
        if (c >= lo && c < hi) atomicAdd(&deg[c], 1);
    }
}

__global__ __launch_bounds__(256) void scan1_kernel(const int* __restrict__ deg,
                                                    int* __restrict__ local,
                                                    int* __restrict__ blocksums, int n) {
    __shared__ int wsum[4];
    const int t = threadIdx.x;
    const int lane = t & 63;
    const int wv = t >> 6;
    const int base = blockIdx.x * 1024 + t * 4;
    int a0 = (base + 0 < n) ? deg[base + 0] : 0;
    int a1 = (base + 1 < n) ? deg[base + 1] : 0;
    int a2 = (base + 2 < n) ? deg[base + 2] : 0;
    int a3 = (base + 3 < n) ? deg[base + 3] : 0;
    const int tot = a0 + a1 + a2 + a3;
    int incl = tot;
#pragma unroll
    for (int off = 1; off < 64; off <<= 1) {
        int u = __shfl_up(incl, off);
        if (lane >= off) incl += u;
    }
    if (lane == 63) wsum[wv] = incl;
    __syncthreads();
    int woff = 0;
#pragma unroll
    for (int w = 0; w < 4; ++w) woff += (w < wv) ? wsum[w] : 0;
    const int excl = woff + incl - tot;
    if (base + 0 < n) local[base + 0] = excl;
    if (base + 1 < n) local[base + 1] = excl + a0;
    if (base + 2 < n) local[base + 2] = excl + a0 + a1;
    if (base + 3 < n) local[base + 3] = excl + a0 + a1 + a2;
    if (t == 255) blocksums[blockIdx.x] = woff + incl;
}

__global__ void scan2_kernel(const int* __restrict__ blocksums, int* __restrict__ blockoff,
                             int* __restrict__ rowptr, int nb, int n) {
    const int lane = threadIdx.x;  // 64 threads
    int v = (lane < nb) ? blocksums[lane] : 0;
    int incl = v;
#pragma unroll
    for (int off = 1; off < 64; off <<= 1) {
        int u = __shfl_up(incl, off);
        if (lane >= off) incl += u;
    }
    if (lane < nb) blockoff[lane] = incl - v;
    if (lane == 63) rowptr[n] = incl;
}

__global__ void scan3_kernel(const int* __restrict__ local, const int* __restrict__ blockoff,
                             const int* __restrict__ deg, int* __restrict__ rowptr,
                             int* __restrict__ cursor, float* __restrict__ dinv, int n) {
    int i = blockIdx.x * blockDim.x + threadIdx.x;
    if (i < n) {
        const int v = local[i] + blockoff[i >> 10];
        rowptr[i] = v;
        cursor[i] = v;
        dinv[i] = rsqrtf((float)deg[i] + 1.0f);
    }
}

__global__ __launch_bounds__(256) void fill_part_kernel(const int* __restrict__ row,
                                                        const int* __restrict__ col,
                                                        int* __restrict__ cursor,
                                                        int* __restrict__ csr, int E, int n) {
    const int part = blockIdx.x & 7;
    const int nb = gridDim.x >> 3;
    const int chunk = blockIdx.x >> 3;
    const int lo = (int)(((long long)part * n) >> 3);
    const int hi = (int)(((long long)(part + 1) * n) >> 3);
    for (int e = chunk * 256 + threadIdx.x; e < E; e += nb * 256) {
        const int c = col[e];
        if (c >= lo && c < hi) {
            const int r = row[e];
            if ((unsigned)r < (unsigned)n) {
                const int pos = atomicAdd(&cursor[c], 1);
                csr[pos] = r;
            }
        }
    }
}

// h[:, c0:c0+COLS] = X @ W[:, c0:c0+COLS], row r scaled by dinv[r].
// W column-slab staged in LDS (COLS=64 -> 32KB -> 5 blocks/CU). R=4 rows
// register-blocked per thread: 16 LDS floats feed 64 FMAs.
// CM: output chunk-major [OUT/16][n][16]; else row-major [n][OUT].
template <int OUT, int COLS, bool CM>
__global__ __launch_bounds__(256) void gemm_kernel(const float* __restrict__ X,
                                                   const float* __restrict__ W,
                                                   const float* __restrict__ dinv,
                                                   float* __restrict__ out, int n) {
    constexpr int NSLAB = OUT / COLS;
    constexpr int CQ  = COLS / 4;
    constexpr int RG  = 256 / CQ;
    constexpr int R   = 4;
    constexpr int RPI = RG * R;
    __shared__ float Wl[128 * COLS];

    const int t = threadIdx.x;
    const int c0 = (int)(blockIdx.x % NSLAB) * COLS;
    const int rowblk = blockIdx.x / NSLAB;

    for (int i = t; i < 128 * CQ; i += 256) {
        const int k  = i / CQ;
        const int cc = i % CQ;
        ((float4*)Wl)[i] = *(const float4*)&W[(size_t)k * OUT + c0 + cc * 4];
    }
    __syncthreads();

    const int cq = t % CQ;
    const int rg = t / CQ;
    const float4* X4 = (const float4*)X;
    const int gcol = c0 + cq * 4;                 // global output column
    const size_t cm_base = (size_t)(gcol >> 4) * n * 16 + (gcol & 15);

    const int r0 = rowblk * RPI + rg * R;
    float4 acc[R];
#pragma unroll
    for (int r = 0; r < R; ++r) acc[r] = make_float4(0.f, 0.f, 0.f, 0.f);

    if (r0 + R <= n) {
#pragma unroll 4
        for (int k4 = 0; k4 < 32; ++k4) {
            const float* wp = &Wl[k4 * 4 * COLS + cq * 4];
            float4 w0 = *(const float4*)(wp);
            float4 w1 = *(const float4*)(wp + COLS);
            float4 w2 = *(const float4*)(wp + 2 * COLS);
            float4 w3 = *(const float4*)(wp + 3 * COLS);
#pragma unroll
            for (int r = 0; r < R; ++r) {
                float4 xv = X4[(size_t)(r0 + r) * 32 + k4];
                acc[r].x = fmaf(xv.x, w0.x, acc[r].x);
                acc[r].x = fmaf(xv.y, w1.x, acc[r].x);
                acc[r].x = fmaf(xv.z, w2.x, acc[r].x);
                acc[r].x = fmaf(xv.w, w3.x, acc[r].x);
                acc[r].y = fmaf(xv.x, w0.y, acc[r].y);
                acc[r].y = fmaf(xv.y, w1.y, acc[r].y);
                acc[r].y = fmaf(xv.z, w2.y, acc[r].y);
                acc[r].y = fmaf(xv.w, w3.y, acc[r].y);
                acc[r].z = fmaf(xv.x, w0.z, acc[r].z);
                acc[r].z = fmaf(xv.y, w1.z, acc[r].z);
                acc[r].z = fmaf(xv.z, w2.z, acc[r].z);
                acc[r].z = fmaf(xv.w, w3.z, acc[r].z);
                acc[r].w = fmaf(xv.x, w0.w, acc[r].w);
                acc[r].w = fmaf(xv.y, w1.w, acc[r].w);
                acc[r].w = fmaf(xv.z, w2.w, acc[r].w);
                acc[r].w = fmaf(xv.w, w3.w, acc[r].w);
            }
        }
#pragma unroll
        for (int r = 0; r < R; ++r) {
            const float s = dinv[r0 + r];
            acc[r].x *= s; acc[r].y *= s; acc[r].z *= s; acc[r].w *= s;
            float* dst = CM ? &out[cm_base + (size_t)(r0 + r) * 16]
                            : &out[(size_t)(r0 + r) * OUT + gcol];
            *(float4*)dst = acc[r];
        }
    } else if (r0 < n) {
        for (int r = 0; r < R; ++r) {
            const int row = r0 + r;
            if (row >= n) break;
            float4 a = make_float4(0.f, 0.f, 0.f, 0.f);
            for (int k4 = 0; k4 < 32; ++k4) {
                float4 xv = X4[(size_t)row * 32 + k4];
                const float* wp = &Wl[k4 * 4 * COLS + cq * 4];
                float4 w0 = *(const float4*)(wp);
                float4 w1 = *(const float4*)(wp + COLS);
                float4 w2 = *(const float4*)(wp + 2 * COLS);
                float4 w3 = *(const float4*)(wp + 3 * COLS);
                a.x = fmaf(xv.x, w0.x, a.x); a.x = fmaf(xv.y, w1.x, a.x);
                a.x = fmaf(xv.z, w2.x, a.x); a.x = fmaf(xv.w, w3.x, a.x);
                a.y = fmaf(xv.x, w0.y, a.y); a.y = fmaf(xv.y, w1.y, a.y);
                a.y = fmaf(xv.z, w2.y, a.y); a.y = fmaf(xv.w, w3.y, a.y);
                a.z = fmaf(xv.x, w0.z, a.z); a.z = fmaf(xv.y, w1.z, a.z);
                a.z = fmaf(xv.z, w2.z, a.z); a.z = fmaf(xv.w, w3.z, a.z);
                a.w = fmaf(xv.x, w0.w, a.w); a.w = fmaf(xv.y, w1.w, a.w);
                a.w = fmaf(xv.z, w2.w, a.w); a.w = fmaf(xv.w, w3.w, a.w);
            }
            const float s = dinv[row];
            a.x *= s; a.y *= s; a.z *= s; a.w *= s;
            float* dst = CM ? &out[cm_base + (size_t)row * 16]
                            : &out[(size_t)row * OUT + gcol];
            *(float4*)dst = a;
        }
    }
}

// XCD-local chunked aggregate (F=128). hc chunk-major [8][n][16]; block owns
// chunk blockIdx%8 (round-robin -> XCD-private, L2-resident 3.2MB slice).
// 4 lanes x float4 per node, 64 nodes/block, 8-deep predicated unroll.
// Output row-major [n][128].
template <bool RELU>
__global__ __launch_bounds__(256) void agg_chunk_kernel(const float* __restrict__ hc,
                                                        const int* __restrict__ rowptr,
                                                        const int* __restrict__ csr,
                                                        const float* __restrict__ dinv,
                                                        const float* __restrict__ bias,
                                                        float* __restrict__ out, int n) {
    const int t = threadIdx.x;
    const int cc = blockIdx.x & 7;            // chunk / XCD slot
    const int g  = blockIdx.x >> 3;           // node-group (64 nodes)
    const int node = g * 64 + (t >> 2);
    const int fo = t & 3;                     // float4 index within chunk
    if (node >= n) return;

    const float4* h4 = (const float4*)(hc + (size_t)cc * n * 16);
    float4 self = h4[(size_t)node * 4 + fo];
    float4 a[8];
#pragma unroll
    for (int j = 0; j < 8; ++j) a[j] = make_float4(0.f, 0.f, 0.f, 0.f);

    const int s = rowptr[node];
    const int e = rowptr[node + 1];
    for (int i = s; i < e; i += 8) {
        int   idx[8];
        float msk[8];
#pragma unroll
        for (int j = 0; j < 8; ++j) {
            const int k = i + j;
            const int kc = (k < e) ? k : (e - 1);
            idx[j] = csr[kc];
            msk[j] = (k < e) ? 1.f : 0.f;
        }
#pragma unroll
        for (int j = 0; j < 8; ++j) {
            float4 v = h4[(size_t)idx[j] * 4 + fo];
            a[j].x = fmaf(v.x, msk[j], a[j].x);
            a[j].y = fmaf(v.y, msk[j], a[j].y);
            a[j].z = fmaf(v.z, msk[j], a[j].z);
            a[j].w = fmaf(v.w, msk[j], a[j].w);
        }
    }
    float accx = self.x + ((a[0].x + a[1].x) + (a[2].x + a[3].x)) + ((a[4].x + a[5].x) + (a[6].x + a[7].x));
    float accy = self.y + ((a[0].y + a[1].y) + (a[2].y + a[3].y)) + ((a[4].y + a[5].y) + (a[6].y + a[7].y));
    float accz = self.z + ((a[0].z + a[1].z) + (a[2].z + a[3].z)) + ((a[4].z + a[5].z) + (a[6].z + a[7].z));
    float accw = self.w + ((a[0].w + a[1].w) + (a[2].w + a[3].w)) + ((a[4].w + a[5].w) + (a[6].w + a[7].w));
    const float dc = dinv[node];
    const int f = cc * 16 + fo * 4;
    const float4 b = *(const float4*)&bias[f];
    float ox = fmaf(accx, dc, b.x);
    float oy = fmaf(accy, dc, b.y);
    float oz = fmaf(accz, dc, b.z);
    float ow = fmaf(accw, dc, b.w);
    if (RELU) {
        ox = fmaxf(ox, 0.f); oy = fmaxf(oy, 0.f);
        oz = fmaxf(oz, 0.f); ow = fmaxf(ow, 0.f);
    }
    float4 res = {ox, oy, oz, ow};
    *(float4*)&out[(size_t)node * 128 + f] = res;
}

// Row-major aggregate (layer 3, F=32): float4 lanes, 8-deep pred. unroll.
template <int F, bool RELU>
__global__ __launch_bounds__(256) void agg_kernel(const float* __restrict__ hs,
                                                  const int* __restrict__ rowptr,
                                                  const int* __restrict__ csr,
                                                  const float* __restrict__ dinv,
                                                  const float* __restrict__ bias,
                                                  float* __restrict__ out, int n) {
    constexpr int LPN = F / 4;
    constexpr int NPB = 256 / LPN;
    constexpr int F4  = F / 4;
    const int t = threadIdx.x;
    const int node = blockIdx.x * NPB + t / LPN;
    const int fo = t % LPN;
    if (node >= n) return;

    const float4* h4 = (const float4*)hs;
    float4 self = h4[(size_t)node * F4 + fo];
    float4 a[8];
#pragma unroll
    for (int j = 0; j < 8; ++j) a[j] = make_float4(0.f, 0.f, 0.f, 0.f);

    const int s = rowptr[node];
    const int e = rowptr[node + 1];
    for (int i = s; i < e; i += 8) {
        int   idx[8];
        float msk[8];
#pragma unroll
        for (int j = 0; j < 8; ++j) {
            const int k = i + j;
            const int kc = (k < e) ? k : (e - 1);
            idx[j] = csr[kc];
            msk[j] = (k < e) ? 1.f : 0.f;
        }
#pragma unroll
        for (int j = 0; j < 8; ++j) {
            float4 v = h4[(size_t)idx[j] * F4 + fo];
            a[j].x = fmaf(v.x, msk[j], a[j].x);
            a[j].y = fmaf(v.y, msk[j], a[j].y);
            a[j].z = fmaf(v.z, msk[j], a[j].z);
            a[j].w = fmaf(v.w, msk[j], a[j].w);
        }
    }
    float accx = self.x + ((a[0].x + a[1].x) + (a[2].x + a[3].x)) + ((a[4].x + a[5].x) + (a[6].x + a[7].x));
    float accy = self.y + ((a[0].y + a[1].y) + (a[2].y + a[3].y)) + ((a[4].y + a[5].y) + (a[6].y + a[7].y));
    float accz = self.z + ((a[0].z + a[1].z) + (a[2].z + a[3].z)) + ((a[4].z + a[5].z) + (a[6].z + a[7].z));
    float accw = self.w + ((a[0].w + a[1].w) + (a[2].w + a[3].w)) + ((a[4].w + a[5].w) + (a[6].w + a[7].w));
    const float dc = dinv[node];
    const float4 b = *(const float4*)&bias[fo * 4];
    float ox = fmaf(accx, dc, b.x);
    float oy = fmaf(accy, dc, b.y);
    float oz = fmaf(accz, dc, b.z);
    float ow = fmaf(accw, dc, b.w);
    if (RELU) {
        ox = fmaxf(ox, 0.f); oy = fmaxf(oy, 0.f);
        oz = fmaxf(oz, 0.f); ow = fmaxf(ow, 0.f);
    }
    float4 res = {ox, oy, oz, ow};
    *(float4*)&out[(size_t)node * F + fo * 4] = res;
}

extern "C" void kernel_launch(void* const* d_in, const int* in_sizes, int n_in,
                              void* d_out, int out_size, void* d_ws, size_t ws_size,
                              hipStream_t stream) {
    const float* x  = (const float*)d_in[0];
    const int*   ei = (const int*)d_in[1];
    // d_in[2] = batch (unused in eval forward)
    const float* W1 = (const float*)d_in[3];
    const float* b1 = (const float*)d_in[4];
    const float* W2 = (const float*)d_in[5];
    const float* b2 = (const float*)d_in[6];
    const float* W3 = (const float*)d_in[7];
    const float* b3 = (const float*)d_in[8];
    float* out = (float*)d_out;

    const int N = in_sizes[0] / 128;
    const int E = in_sizes[1] / 2;
    const int* erow = ei;       // sources
    const int* ecol = ei + E;   // destinations

    // Workspace layout — round-1-proven footprint (55,200,768 B).
    char* ws = (char*)d_ws;
    auto alloc = [&](size_t bytes) {
        char* p = ws;
        ws += (bytes + 255) & ~(size_t)255;
        return p;
    };
    int*   deg    = (int*)alloc((size_t)N * 4);
    int*   rowptr = (int*)alloc((size_t)(N + 1) * 4);
    int*   cursor = (int*)alloc((size_t)N * 4);
    int*   csr    = (int*)alloc((size_t)E * 4);
    float* dinv   = (float*)alloc((size_t)N * 4);
    float* buf1   = (float*)alloc((size_t)N * 128 * 4);
    float* buf2   = (float*)alloc((size_t)N * 128 * 4);

    // Scan temporaries alias buf1 (dead until first GEMM writes it).
    int* local = (int*)buf1;
    int* bsums = local + N;
    int* boffs = bsums + 64;

    const int nb = (N + 1023) / 1024;  // scan2 assumes nb <= 64

    hipMemsetAsync(deg, 0, (size_t)N * 4, stream);
    count_part_kernel<<<8 * 128, 256, 0, stream>>>(ecol, deg, E, N);
    scan1_kernel<<<nb, 256, 0, stream>>>(deg, local, bsums, N);
    scan2_kernel<<<1, 64, 0, stream>>>(bsums, boffs, rowptr, nb, N);
    scan3_kernel<<<(N + 255) / 256, 256, 0, stream>>>(local, boffs, deg, rowptr, cursor, dinv, N);
    fill_part_kernel<<<8 * 128, 256, 0, stream>>>(erow, ecol, cursor, csr, E, N);

    const int g128 = ((N + 63) / 64) * 2;      // gemm<128,64>: RPI=64, 2 slabs
    const int g32  = (N + 127) / 128;          // gemm<32,32>:  RPI=128, 1 slab
    const int gagg = ((N + 63) / 64) * 8;      // agg_chunk: 64 nodes x 8 chunks

    // Layer 1: chunk-major GEMM, XCD-local chunked agg
    gemm_kernel<128, 64, true><<<g128, 256, 0, stream>>>(x, W1, dinv, buf1, N);
    agg_chunk_kernel<true><<<gagg, 256, 0, stream>>>(buf1, rowptr, csr, dinv, b1, buf2, N);

    // Layer 2
    gemm_kernel<128, 64, true><<<g128, 256, 0, stream>>>(buf2, W2, dinv, buf1, N);
    agg_chunk_kernel<true><<<gagg, 256, 0, stream>>>(buf1, rowptr, csr, dinv, b2, buf2, N);

    // Layer 3: logits (no relu), 32 classes -> d_out
    gemm_kernel<32, 32, false><<<g32, 256, 0, stream>>>(buf2, W3, dinv, buf1, N);
    agg_kernel<32, false><<<(N + 31) / 32, 256, 0, stream>>>(buf1, rowptr, csr, dinv, b3, out, N);
}